// Round 1
// baseline (281.594 us; speedup 1.0000x reference)
//
#include <hip/hip_runtime.h>

// Problem constants
#define BB 2
#define CC 64
#define GG 8
#define CPG 8        // C per group
#define KK 27
#define KG 216       // K*G
#define DIM 32
#define S_TOT 32768  // 32^3
#define BN_EPS 1e-5f

// ---------------------------------------------------------------------------
// Kernel A: fused GEMM1 (w_reduce) + BN + ReLU + GEMM2 (w_span) -> ker in ws
// Block: 256 threads, handles (b, 64-wide spatial tile). Grid = 2*512 = 1024.
// ---------------------------------------------------------------------------
__global__ __launch_bounds__(256) void kergen_kernel(
    const float* __restrict__ x, const float* __restrict__ wr,
    const float* __restrict__ wsp, const float* __restrict__ gamma,
    const float* __restrict__ beta, const float* __restrict__ mean,
    const float* __restrict__ var, float* __restrict__ ker) {
  __shared__ float xs[CC][64];   // 16 KB  (c x s)
  __shared__ float sv[CC][64];   // 16 KB  (c x s) post BN+ReLU
  const int blk = blockIdx.x;
  const int b   = blk >> 9;            // 512 tiles per batch
  const int s0  = (blk & 511) << 6;
  const int tid = threadIdx.x;

  const float* xb = x + ((size_t)b << 21);  // b*64*32768
  for (int i = tid; i < CC * 64; i += 256) {
    int c = i >> 6, si = i & 63;
    xs[c][si] = xb[((size_t)c << 15) + s0 + si];
  }
  __syncthreads();

  const int si    = tid & 63;
  const int lane4 = __builtin_amdgcn_readfirstlane(tid >> 6);  // wave-uniform

  // GEMM1: each thread computes 16 output channels (o = lane4 + 4j) at si
  {
    float acc[16];
#pragma unroll
    for (int j = 0; j < 16; ++j) acc[j] = 0.f;
    for (int c = 0; c < CC; ++c) {
      float xv = xs[c][si];
#pragma unroll
      for (int j = 0; j < 16; ++j)
        acc[j] = fmaf(wr[(lane4 + 4 * j) * CC + c], xv, acc[j]);
    }
#pragma unroll
    for (int j = 0; j < 16; ++j) {
      int o = lane4 + 4 * j;
      float iv = rsqrtf(var[o] + BN_EPS);
      float v  = (acc[j] - mean[o]) * iv * gamma[o] + beta[o];
      sv[o][si] = v > 0.f ? v : 0.f;
    }
  }
  __syncthreads();

  // GEMM2: each thread computes 54 kernel channels (kg = lane4 + 4j) at si
  {
    float acc[54];
#pragma unroll
    for (int j = 0; j < 54; ++j) acc[j] = 0.f;
    for (int c = 0; c < CC; ++c) {
      float xv = sv[c][si];
#pragma unroll
      for (int j = 0; j < 54; ++j)
        acc[j] = fmaf(wsp[(lane4 + 4 * j) * CC + c], xv, acc[j]);
    }
    float* kb = ker + (((size_t)b * KG) << 15);
#pragma unroll
    for (int j = 0; j < 54; ++j) {
      int kg = lane4 + 4 * j;
      kb[((size_t)kg << 15) + s0 + si] = acc[j];
    }
  }
}

// ---------------------------------------------------------------------------
// Kernel B: involution gather-reduce.
// out[b,c,s] = sum_k ker[b, g*27+k, s] * x[b,c, decode(k*32768+s)]
// decode: f in mixed radix [od:32][oh:32][ow:32][kd:3][kh:3][kw:3],
//         (dd,hh,ww) = (od+kd-1, oh+kh-1, ow+kw-1), 0 if OOB (padding).
// Block: 256 threads, handles (b, g, 128-wide spatial tile). Grid = 4096.
// ---------------------------------------------------------------------------
__global__ __launch_bounds__(256) void invol_kernel(
    const float* __restrict__ x, const float* __restrict__ ker,
    float* __restrict__ out) {
  __shared__ float kl[KK][128];  // 13.5 KB
  const int blk = blockIdx.x;
  const int b   = blk >> 11;
  const int g   = (blk >> 8) & 7;
  const int s0  = (blk & 255) << 7;
  const int tid = threadIdx.x;

  const float* kb = ker + (((size_t)b * KG + g * KK) << 15);
  for (int i = tid; i < KK * 128; i += 256) {
    int k = i >> 7, sj = i & 127;
    kl[k][sj] = kb[((size_t)k << 15) + s0 + sj];
  }
  __syncthreads();

  const float* xb = x + ((size_t)b << 21);
#pragma unroll
  for (int t = 0; t < 4; ++t) {
    int lin = (t << 8) + tid;
    int cg  = lin >> 7, sj = lin & 127;
    int c   = (g << 3) + cg;
    int s   = s0 + sj;
    const float* xc = xb + ((size_t)c << 15);
    float acc = 0.f;
#pragma unroll
    for (int k = 0; k < KK; ++k) {
      int f  = (k << 15) + s;
      int kw = f % 3; int u = f / 3;
      int kh = u % 3; u /= 3;
      int kd = u % 3; u /= 3;
      int ww = (u & 31) + kw - 1; u >>= 5;
      int hh = (u & 31) + kh - 1; u >>= 5;
      int dd = u + kd - 1;
      float xv = 0.f;
      if ((unsigned)ww < 32u && (unsigned)hh < 32u && (unsigned)dd < 32u)
        xv = xc[(dd << 10) + (hh << 5) + ww];
      acc = fmaf(kl[k][sj], xv, acc);
    }
    out[(((size_t)b * CC + c) << 15) + s] = acc;
  }
}

// ---------------------------------------------------------------------------
// Fallback: fully fused, zero workspace. Block handles (b, g, 64-wide tile),
// recomputes GEMM1 per group (8x redundant) but needs no ker buffer.
// Grid = 2*8*512 = 8192.
// ---------------------------------------------------------------------------
__global__ __launch_bounds__(256) void invol_fused_kernel(
    const float* __restrict__ x, const float* __restrict__ wr,
    const float* __restrict__ wsp, const float* __restrict__ gamma,
    const float* __restrict__ beta, const float* __restrict__ mean,
    const float* __restrict__ var, float* __restrict__ out) {
  __shared__ float xs[CC][64];
  __shared__ float sv[CC][64];
  __shared__ float kl[KK][64];
  const int blk = blockIdx.x;
  const int b   = blk >> 12;
  const int g   = (blk >> 9) & 7;
  const int s0  = (blk & 511) << 6;
  const int tid = threadIdx.x;

  const float* xb = x + ((size_t)b << 21);
  for (int i = tid; i < CC * 64; i += 256) {
    int c = i >> 6, si = i & 63;
    xs[c][si] = xb[((size_t)c << 15) + s0 + si];
  }
  __syncthreads();

  const int si    = tid & 63;
  const int lane4 = __builtin_amdgcn_readfirstlane(tid >> 6);
  {
    float acc[16];
#pragma unroll
    for (int j = 0; j < 16; ++j) acc[j] = 0.f;
    for (int c = 0; c < CC; ++c) {
      float xv = xs[c][si];
#pragma unroll
      for (int j = 0; j < 16; ++j)
        acc[j] = fmaf(wr[(lane4 + 4 * j) * CC + c], xv, acc[j]);
    }
#pragma unroll
    for (int j = 0; j < 16; ++j) {
      int o = lane4 + 4 * j;
      float iv = rsqrtf(var[o] + BN_EPS);
      float v  = (acc[j] - mean[o]) * iv * gamma[o] + beta[o];
      sv[o][si] = v > 0.f ? v : 0.f;
    }
  }
  __syncthreads();

  for (int i = tid; i < KK * 64; i += 256) {
    int k = i >> 6, sj = i & 63;
    int kg = g * KK + k;
    float acc = 0.f;
    for (int c = 0; c < CC; ++c)
      acc = fmaf(wsp[kg * CC + c], sv[c][sj], acc);
    kl[k][sj] = acc;
  }
  __syncthreads();

#pragma unroll
  for (int t = 0; t < 2; ++t) {
    int lin = (t << 8) + tid;
    int cg  = lin >> 6, sj = lin & 63;
    int c   = (g << 3) + cg;
    int s   = s0 + sj;
    const float* xc = xb + ((size_t)c << 15);
    float acc = 0.f;
#pragma unroll
    for (int k = 0; k < KK; ++k) {
      int f  = (k << 15) + s;
      int kw = f % 3; int u = f / 3;
      int kh = u % 3; u /= 3;
      int kd = u % 3; u /= 3;
      int ww = (u & 31) + kw - 1; u >>= 5;
      int hh = (u & 31) + kh - 1; u >>= 5;
      int dd = u + kd - 1;
      float xv = 0.f;
      if ((unsigned)ww < 32u && (unsigned)hh < 32u && (unsigned)dd < 32u)
        xv = xc[(dd << 10) + (hh << 5) + ww];
      acc = fmaf(kl[k][sj], xv, acc);
    }
    out[(((size_t)b * CC + c) << 15) + s] = acc;
  }
}

extern "C" void kernel_launch(void* const* d_in, const int* in_sizes, int n_in,
                              void* d_out, int out_size, void* d_ws, size_t ws_size,
                              hipStream_t stream) {
  const float* x     = (const float*)d_in[0];
  const float* wr    = (const float*)d_in[1];
  const float* wsp   = (const float*)d_in[2];
  const float* gamma = (const float*)d_in[3];
  const float* beta  = (const float*)d_in[4];
  const float* mean  = (const float*)d_in[5];
  const float* var   = (const float*)d_in[6];
  float* out = (float*)d_out;

  const size_t ker_bytes = (size_t)BB * KG * S_TOT * sizeof(float);  // 56.6 MB
  if (ws_size >= ker_bytes) {
    float* ker = (float*)d_ws;
    kergen_kernel<<<BB * (S_TOT / 64), 256, 0, stream>>>(
        x, wr, wsp, gamma, beta, mean, var, ker);
    invol_kernel<<<BB * GG * (S_TOT / 128), 256, 0, stream>>>(x, ker, out);
  } else {
    invol_fused_kernel<<<BB * GG * (S_TOT / 64), 256, 0, stream>>>(
        x, wr, wsp, gamma, beta, mean, var, out);
  }
}

// Round 2
// 213.451 us; speedup vs baseline: 1.3192x; 1.3192x over previous
//
#include <hip/hip_runtime.h>

// Problem constants
#define BB 2
#define CC 64
#define GG 8
#define KK 27
#define KG 216       // K*G
#define S_TOT 32768  // 32^3
#define BN_EPS 1e-5f

// ---------------------------------------------------------------------------
// Single fused kernel. Block = 256 threads (4 waves), handles (b, 64-wide
// spatial tile). Grid = 2 * 512 = 1024.
//   Phase 0: stage x tile (64c x 64s) in LDS
//   Phase 1: GEMM1 (w_reduce) + BN + ReLU -> sv in LDS
//            each wave owns 16 output channels; per-thread xv[64] in VGPRs,
//            weight rows are contiguous + wave-uniform -> s_load streams
//   Phase 2: GEMM2 (w_span) -> ker (216 x 64) in LDS (aliases xs)
//            each wave owns 54 kernel-channels
//   Phase 3: involution gather-reduce; each thread owns 16 channels at one
//            spatial position; decode computed once per (k, s).
// LDS: sv 16KB + ker 54KB = 70KB -> 2 blocks/CU.
// ---------------------------------------------------------------------------
__global__ __launch_bounds__(256, 2) void invol_onepass(
    const float* __restrict__ x, const float* __restrict__ wr,
    const float* __restrict__ wsp, const float* __restrict__ gamma,
    const float* __restrict__ beta, const float* __restrict__ mean,
    const float* __restrict__ var, float* __restrict__ out) {
  __shared__ float smem[4096 + KG * 64];  // sv[64][64] | ker[216][64]
  float* sv   = smem;
  float* kerl = smem + 4096;
  float* xs   = smem + 4096;  // alias: xs dead once ker is written

  const int tid = threadIdx.x;
  const int blk = blockIdx.x;
  const int b   = blk >> 9;
  const int s0  = (blk & 511) << 6;
  const int si  = tid & 63;
  const int w   = __builtin_amdgcn_readfirstlane(tid >> 6);  // wave id 0..3

  const float* xb = x + ((size_t)b << 21);

  // ---- Phase 0: stage x tile (vectorized float4) ----
  for (int i = tid; i < 64 * 16; i += 256) {
    int c = i >> 4, q = (i & 15) << 2;
    float4 v = *(const float4*)(xb + ((size_t)c << 15) + s0 + q);
    *(float4*)(xs + c * 64 + q) = v;
  }
  __syncthreads();

  // ---- Phase 1: GEMM1 + BN + ReLU -> sv ----
  {
    float xv[64];
#pragma unroll
    for (int c = 0; c < 64; ++c) xv[c] = xs[c * 64 + si];

    const float* wrw = wr + w * 16 * CC;
#pragma unroll
    for (int j = 0; j < 16; j += 2) {
      const float* r0 = wrw + j * CC;
      const float* r1 = r0 + CC;
      float a00 = 0.f, a01 = 0.f, a10 = 0.f, a11 = 0.f;
#pragma unroll
      for (int c = 0; c < 64; c += 2) {
        a00 = fmaf(r0[c],     xv[c],     a00);
        a01 = fmaf(r0[c + 1], xv[c + 1], a01);
        a10 = fmaf(r1[c],     xv[c],     a10);
        a11 = fmaf(r1[c + 1], xv[c + 1], a11);
      }
      int o0 = w * 16 + j, o1 = o0 + 1;
      float v0 = (a00 + a01 - mean[o0]) * rsqrtf(var[o0] + BN_EPS) * gamma[o0] + beta[o0];
      float v1 = (a10 + a11 - mean[o1]) * rsqrtf(var[o1] + BN_EPS) * gamma[o1] + beta[o1];
      sv[o0 * 64 + si] = v0 > 0.f ? v0 : 0.f;
      sv[o1 * 64 + si] = v1 > 0.f ? v1 : 0.f;
    }
  }
  __syncthreads();

  // ---- Phase 2: GEMM2 -> ker in LDS (overwrites xs region) ----
  {
    float xv[64];
#pragma unroll
    for (int c = 0; c < 64; ++c) xv[c] = sv[c * 64 + si];

    const float* wsw = wsp + w * 54 * CC;
#pragma unroll
    for (int j = 0; j < 54; j += 2) {
      const float* r0 = wsw + j * CC;
      const float* r1 = r0 + CC;
      float a00 = 0.f, a01 = 0.f, a10 = 0.f, a11 = 0.f;
#pragma unroll
      for (int c = 0; c < 64; c += 2) {
        a00 = fmaf(r0[c],     xv[c],     a00);
        a01 = fmaf(r0[c + 1], xv[c + 1], a01);
        a10 = fmaf(r1[c],     xv[c],     a10);
        a11 = fmaf(r1[c + 1], xv[c + 1], a11);
      }
      int row = w * 54 + j;
      kerl[row * 64 + si]       = a00 + a01;
      kerl[(row + 1) * 64 + si] = a10 + a11;
    }
  }
  __syncthreads();

  // ---- Phase 3: involution gather-reduce ----
  // out[b,c,s] = sum_k ker[g(c)*27+k, s] * x[b,c, decode(k*32768+s)]
  // decode: f in mixed radix [od:32][oh:32][ow:32][kd:3][kh:3][kw:3],
  //         (dd,hh,ww) = (od+kd-1, oh+kh-1, ow+kw-1), 0 if OOB.
  {
    const int c0 = w << 4;        // 16 channels per wave
    const int g0 = c0 >> 3;       // two groups: g0, g0+1
    const int s  = s0 + si;
    float acc[16];
#pragma unroll
    for (int i = 0; i < 16; ++i) acc[i] = 0.f;

    for (int k = 0; k < KK; ++k) {
      int f  = (k << 15) + s;
      int kw = f % 3; int u = f / 3;
      int kh = u % 3; u /= 3;
      int kd = u % 3; u /= 3;
      int ww = (u & 31) + kw - 1; u >>= 5;
      int hh = (u & 31) + kh - 1; u >>= 5;
      int dd = u + kd - 1;
      float kv0 = kerl[(g0 * KK + k) * 64 + si];
      float kv1 = kerl[((g0 + 1) * KK + k) * 64 + si];
      if (((unsigned)ww < 32u) & ((unsigned)hh < 32u) & ((unsigned)dd < 32u)) {
        const float* xp = xb + ((size_t)c0 << 15) + (dd << 10) + (hh << 5) + ww;
#pragma unroll
        for (int c8 = 0; c8 < 8; ++c8) {
          acc[c8]     = fmaf(kv0, xp[(size_t)c8 << 15],       acc[c8]);
          acc[c8 + 8] = fmaf(kv1, xp[(size_t)(c8 + 8) << 15], acc[c8 + 8]);
        }
      }
    }

    float* ob = out + (((size_t)b * CC + c0) << 15) + s;
#pragma unroll
    for (int i = 0; i < 16; ++i) ob[(size_t)i << 15] = acc[i];
  }
}

extern "C" void kernel_launch(void* const* d_in, const int* in_sizes, int n_in,
                              void* d_out, int out_size, void* d_ws, size_t ws_size,
                              hipStream_t stream) {
  const float* x     = (const float*)d_in[0];
  const float* wr    = (const float*)d_in[1];
  const float* wsp   = (const float*)d_in[2];
  const float* gamma = (const float*)d_in[3];
  const float* beta  = (const float*)d_in[4];
  const float* mean  = (const float*)d_in[5];
  const float* var   = (const float*)d_in[6];
  float* out = (float*)d_out;

  invol_onepass<<<BB * (S_TOT / 64), 256, 0, stream>>>(
      x, wr, wsp, gamma, beta, mean, var, out);
}

// Round 3
// 155.622 us; speedup vs baseline: 1.8095x; 1.3716x over previous
//
#include <hip/hip_runtime.h>

// Problem constants
#define BB 2
#define CC 64
#define KK 27
#define S_TOT 32768  // 32^3
#define BN_EPS 1e-5f

// ---------------------------------------------------------------------------
// Single fused kernel. Block = 256 threads (4 waves), handles (b, 64-wide
// spatial tile). Grid = 2 * 512 = 1024.
//   Phase 1: GEMM1 (w_reduce) + BN + ReLU -> sv in LDS (16 KB).
//            x read directly from global (per-lane coalesced, L2/L3-backed).
//   Phase 2: GEMM2 (w_span) -> kreg[54] PER-THREAD REGISTERS.
//            Wave w computes ker rows 54w..54w+53 at column si — exactly the
//            rows phase 3 (channels 16w..16w+15 = groups 2w,2w+1) consumes.
//            No LDS handoff, no barrier.
//   Phase 3: involution gather-reduce, 16 channels x 1 spatial per thread.
// LDS: 16 KB. VGPR target ~110 -> 4 waves/SIMD (50% occupancy).
// ---------------------------------------------------------------------------
__global__ __launch_bounds__(256, 4) void invol_onepass(
    const float* __restrict__ x, const float* __restrict__ wr,
    const float* __restrict__ wsp, const float* __restrict__ gamma,
    const float* __restrict__ beta, const float* __restrict__ mean,
    const float* __restrict__ var, float* __restrict__ out) {
  __shared__ float sv[CC * 64];  // sv[c][si], 16 KB

  const int tid = threadIdx.x;
  const int blk = blockIdx.x;
  const int b   = blk >> 9;
  const int s0  = (blk & 511) << 6;
  const int si  = tid & 63;
  const int w   = __builtin_amdgcn_readfirstlane(tid >> 6);  // wave id 0..3

  const float* xb  = x + ((size_t)b << 21);
  const float* xs0 = xb + s0 + si;  // x[c][s0+si] = xs0[c<<15]

  // ---- Phase 1: GEMM1 + BN + ReLU -> sv ----
  {
    float acc[16];
#pragma unroll
    for (int j = 0; j < 16; ++j) acc[j] = 0.f;
#pragma unroll
    for (int half = 0; half < 2; ++half) {
      float xv[32];
#pragma unroll
      for (int c = 0; c < 32; ++c)
        xv[c] = xs0[(size_t)(half * 32 + c) << 15];
      const float* wrw = wr + (w * 16) * CC + half * 32;
#pragma unroll
      for (int j = 0; j < 16; j += 2) {
        const float* r0 = wrw + j * CC;
        const float* r1 = r0 + CC;
        float a00 = 0.f, a01 = 0.f, a10 = 0.f, a11 = 0.f;
#pragma unroll
        for (int c = 0; c < 32; c += 2) {
          a00 = fmaf(r0[c],     xv[c],     a00);
          a01 = fmaf(r0[c + 1], xv[c + 1], a01);
          a10 = fmaf(r1[c],     xv[c],     a10);
          a11 = fmaf(r1[c + 1], xv[c + 1], a11);
        }
        acc[j]     += a00 + a01;
        acc[j + 1] += a10 + a11;
      }
    }
#pragma unroll
    for (int j = 0; j < 16; ++j) {
      int o = w * 16 + j;
      float v = (acc[j] - mean[o]) * rsqrtf(var[o] + BN_EPS) * gamma[o] + beta[o];
      sv[o * 64 + si] = v > 0.f ? v : 0.f;
    }
  }
  __syncthreads();

  // ---- Phase 2: GEMM2 -> kreg (registers; no LDS, no barrier after) ----
  float kreg[54];
#pragma unroll
  for (int j = 0; j < 54; ++j) kreg[j] = 0.f;
#pragma unroll
  for (int half = 0; half < 2; ++half) {
    float xv[32];
#pragma unroll
    for (int c = 0; c < 32; ++c) xv[c] = sv[(half * 32 + c) * 64 + si];
    const float* wsw = wsp + (w * 54) * CC + half * 32;
#pragma unroll
    for (int j = 0; j < 54; j += 2) {
      const float* r0 = wsw + j * CC;
      const float* r1 = r0 + CC;
      float a00 = 0.f, a01 = 0.f, a10 = 0.f, a11 = 0.f;
#pragma unroll
      for (int c = 0; c < 32; c += 2) {
        a00 = fmaf(r0[c],     xv[c],     a00);
        a01 = fmaf(r0[c + 1], xv[c + 1], a01);
        a10 = fmaf(r1[c],     xv[c],     a10);
        a11 = fmaf(r1[c + 1], xv[c + 1], a11);
      }
      kreg[j]     += a00 + a01;
      kreg[j + 1] += a10 + a11;
    }
  }

  // ---- Phase 3: involution gather-reduce ----
  // out[b,c,s] = sum_k ker[g(c)*27+k, s] * x[b,c, decode(k*32768+s)]
  // decode: f in mixed radix [od:32][oh:32][ow:32][kd:3][kh:3][kw:3],
  //         (dd,hh,ww) = (od+kd-1, oh+kh-1, ow+kw-1), 0 if OOB.
  // Wave w's kreg[j]: j = k for group 2w, j = 27+k for group 2w+1.
  {
    const int c0 = w << 4;  // 16 channels per wave
    const int s  = s0 + si;
    float oacc[16];
#pragma unroll
    for (int i = 0; i < 16; ++i) oacc[i] = 0.f;
    const float* xc0 = xb + ((size_t)c0 << 15);

#pragma unroll
    for (int k = 0; k < KK; ++k) {
      int f  = (k << 15) + s;
      int kw = f % 3; int u = f / 3;
      int kh = u % 3; u /= 3;
      int kd = u % 3; u /= 3;
      int ww = (u & 31) + kw - 1; u >>= 5;
      int hh = (u & 31) + kh - 1; u >>= 5;
      int dd = u + kd - 1;
      if (((unsigned)ww < 32u) & ((unsigned)hh < 32u) & ((unsigned)dd < 32u)) {
        const float* xp = xc0 + (dd << 10) + (hh << 5) + ww;
        float kv0 = kreg[k], kv1 = kreg[27 + k];
#pragma unroll
        for (int c8 = 0; c8 < 8; ++c8) {
          oacc[c8]     = fmaf(kv0, xp[(size_t)c8 << 15],       oacc[c8]);
          oacc[c8 + 8] = fmaf(kv1, xp[(size_t)(c8 + 8) << 15], oacc[c8 + 8]);
        }
      }
    }

    float* ob = out + (((size_t)b * CC + c0) << 15) + s;
#pragma unroll
    for (int i = 0; i < 16; ++i) ob[(size_t)i << 15] = oacc[i];
  }
}

extern "C" void kernel_launch(void* const* d_in, const int* in_sizes, int n_in,
                              void* d_out, int out_size, void* d_ws, size_t ws_size,
                              hipStream_t stream) {
  const float* x     = (const float*)d_in[0];
  const float* wr    = (const float*)d_in[1];
  const float* wsp   = (const float*)d_in[2];
  const float* gamma = (const float*)d_in[3];
  const float* beta  = (const float*)d_in[4];
  const float* mean  = (const float*)d_in[5];
  const float* var   = (const float*)d_in[6];
  float* out = (float*)d_out;

  invol_onepass<<<BB * (S_TOT / 64), 256, 0, stream>>>(
      x, wr, wsp, gamma, beta, mean, var, out);
}

// Round 4
// 143.880 us; speedup vs baseline: 1.9571x; 1.0816x over previous
//
#include <hip/hip_runtime.h>

// Problem constants
#define BB 2
#define CC 64
#define KK 27
#define S_TOT 32768  // 32^3
#define BN_EPS 1e-5f

// ---------------------------------------------------------------------------
// Single fused kernel. Block = 256 threads (4 waves) handles
// (b, group-half p, 64-wide spatial tile). Grid = 2*2*512 = 2048 (8 blocks/CU,
// fully resident).
//   Phase 0: decode offset table offs[27][64] -> LDS (shared barrier with sv)
//   Phase 1: GEMM1 (w_reduce) + BN + ReLU -> sv[64][64] in LDS (all 64 ch;
//            2x redundant across the two p-blocks — 0.5 GFLOP, noise)
//   Phase 2: GEMM2 -> kreg[27] per-thread regs. Wave w owns group g=4p+w.
//   Phase 3: involution gather-reduce, 8 channels x 1 spatial per thread,
//            offsets from LDS table.
// Register budget: kreg[27]+oacc[8] persistent = 35 -> fits 64-VGPR bucket,
// __launch_bounds__(256,8) = 8 waves/SIMD.
// ---------------------------------------------------------------------------
__global__ __launch_bounds__(256, 8) void invol_onepass(
    const float* __restrict__ x, const float* __restrict__ wr,
    const float* __restrict__ wsp, const float* __restrict__ gamma,
    const float* __restrict__ beta, const float* __restrict__ mean,
    const float* __restrict__ var, float* __restrict__ out) {
  __shared__ float sv[CC * 64];     // 16 KB
  __shared__ int offs[KK * 64];     // 6.75 KB

  const int tid = threadIdx.x;
  const int blk = blockIdx.x;
  const int b   = blk >> 10;
  const int p   = (blk >> 9) & 1;
  const int s0  = (blk & 511) << 6;
  const int si  = tid & 63;
  const int w   = __builtin_amdgcn_readfirstlane(tid >> 6);  // wave 0..3
  const int g   = (p << 2) + w;                               // group 0..7

  const float* xb  = x + ((size_t)b << 21);
  const float* xs0 = xb + s0 + si;  // x[c][s0+si] = xs0[c<<15]

  // ---- Phase 0: offset table ----
  // f = k*32768 + s in mixed radix [od:32][oh:32][ow:32][kd:3][kh:3][kw:3];
  // (dd,hh,ww) = (od+kd-1, oh+kh-1, ow+kw-1); -1 if OOB (zero padding).
  for (int i = tid; i < KK * 64; i += 256) {
    int k  = i >> 6;
    int f  = (k << 15) + s0 + (i & 63);
    int kw = f % 3; int u = f / 3;
    int kh = u % 3; u /= 3;
    int kd = u % 3; u /= 3;
    int ww = (u & 31) + kw - 1; u >>= 5;
    int hh = (u & 31) + kh - 1; u >>= 5;
    int dd = u + kd - 1;
    int off = -1;
    if (((unsigned)ww < 32u) & ((unsigned)hh < 32u) & ((unsigned)dd < 32u))
      off = (dd << 10) + (hh << 5) + ww;
    offs[i] = off;
  }

  // ---- Phase 1: GEMM1 + BN + ReLU -> sv ----
  {
    float acc[16];
#pragma unroll
    for (int j = 0; j < 16; ++j) acc[j] = 0.f;
#pragma unroll
    for (int half = 0; half < 2; ++half) {
      float xv[32];
#pragma unroll
      for (int c = 0; c < 32; ++c)
        xv[c] = xs0[(size_t)(half * 32 + c) << 15];
      const float* wrw = wr + (w * 16) * CC + half * 32;
#pragma unroll
      for (int j = 0; j < 16; ++j) {
        const float* r0 = wrw + j * CC;
        float a0 = 0.f, a1 = 0.f;
#pragma unroll
        for (int c = 0; c < 32; c += 2) {
          a0 = fmaf(r0[c],     xv[c],     a0);
          a1 = fmaf(r0[c + 1], xv[c + 1], a1);
        }
        acc[j] += a0 + a1;
      }
    }
#pragma unroll
    for (int j = 0; j < 16; ++j) {
      int o = w * 16 + j;
      float v = (acc[j] - mean[o]) * rsqrtf(var[o] + BN_EPS) * gamma[o] + beta[o];
      sv[o * 64 + si] = v > 0.f ? v : 0.f;
    }
  }
  __syncthreads();  // covers offs + sv

  // ---- Phase 2: GEMM2 -> kreg[27] (group g), registers only ----
  float kreg[27];
#pragma unroll
  for (int j = 0; j < KK; ++j) kreg[j] = 0.f;
#pragma unroll
  for (int e = 0; e < 8; ++e) {  // eighths of the c-dimension
    float xv[8];
#pragma unroll
    for (int c = 0; c < 8; ++c) xv[c] = sv[(e * 8 + c) * 64 + si];
    const float* wsw = wsp + (g * KK) * CC + e * 8;
#pragma unroll
    for (int j = 0; j < KK; ++j) {
      const float* r = wsw + j * CC;
      float a0 = 0.f, a1 = 0.f;
#pragma unroll
      for (int c = 0; c < 8; c += 2) {
        a0 = fmaf(r[c],     xv[c],     a0);
        a1 = fmaf(r[c + 1], xv[c + 1], a1);
      }
      kreg[j] += a0 + a1;
    }
  }

  // ---- Phase 3: involution gather-reduce (8 channels) ----
  {
    const int c0 = g << 3;
    const float* xc0 = xb + ((size_t)c0 << 15);
    float oacc[8];
#pragma unroll
    for (int i = 0; i < 8; ++i) oacc[i] = 0.f;

#pragma unroll
    for (int k = 0; k < KK; ++k) {
      int off = offs[(k << 6) + si];
      float kv = kreg[k];
      if (off >= 0) {
#pragma unroll
        for (int c8 = 0; c8 < 8; ++c8)
          oacc[c8] = fmaf(kv, xc0[off + (c8 << 15)], oacc[c8]);
      }
    }

    float* ob = out + (((size_t)b * CC + c0) << 15) + s0 + si;
#pragma unroll
    for (int i = 0; i < 8; ++i) ob[(size_t)i << 15] = oacc[i];
  }
}

extern "C" void kernel_launch(void* const* d_in, const int* in_sizes, int n_in,
                              void* d_out, int out_size, void* d_ws, size_t ws_size,
                              hipStream_t stream) {
  const float* x     = (const float*)d_in[0];
  const float* wr    = (const float*)d_in[1];
  const float* wsp   = (const float*)d_in[2];
  const float* gamma = (const float*)d_in[3];
  const float* beta  = (const float*)d_in[4];
  const float* mean  = (const float*)d_in[5];
  const float* var   = (const float*)d_in[6];
  float* out = (float*)d_out;

  invol_onepass<<<BB * 2 * (S_TOT / 64), 256, 0, stream>>>(
      x, wr, wsp, gamma, beta, mean, var, out);
}